// Round 1
// 309.782 us; speedup vs baseline: 1.2165x; 1.2165x over previous
//
#include <hip/hip_runtime.h>
#include <hip/hip_bf16.h>

#define N_NODES 100000
#define N_EDGES 1600000
#define D       64
#define N_RELS  200
#define LEAKY   0.01f
#define NBUCK   ((N_NODES + 511) / 512)          // 196 coarse buckets, 512 nodes each
#define BIN_CHUNK 4096
#define NBIN    ((N_EDGES + BIN_CHUNK - 1) / BIN_CHUNK)   // 391 binning blocks

typedef __hip_bfloat16 bf16;

__device__ __forceinline__ float b2f(bf16 x) { return __bfloat162float(x); }
__device__ __forceinline__ bf16  f2b(float x) { return __float2bfloat16(x); }

// dtype-dispatching float load: bf==1 -> storage is bf16, else f32 (probe says f32 here)
__device__ __forceinline__ float ldf(const void* p, long i, int bf) {
    return bf ? __bfloat162float(((const bf16*)p)[i]) : ((const float*)p)[i];
}
__device__ __forceinline__ int probe_bf(const void* delta) {
    return ((const unsigned short*)delta)[0] == 0x3F80 ? 1 : 0;
}

// uniform-index lane broadcast via v_readlane (result lands in SGPR)
__device__ __forceinline__ int rl_i(int v, int l) {
    return __builtin_amdgcn_readlane(v, l);
}
__device__ __forceinline__ float rl_f(float v, int l) {
    return __int_as_float(__builtin_amdgcn_readlane(__float_as_int(v), l));
}

// K1: node proj (hWb, s_src, s_dst) + rel proj (relW f32, s_rel) + COARSE dst histogram.
// W1 column held in 64 VGPRs per lane; 4 nodes per wave-iteration (4 indep FMA chains).
// Phase C': LDS-aggregated bucket histogram -> 196 global atomics per block (was 1.6M total).
__global__ __launch_bounds__(512, 4) void k_fused_proj(const void* __restrict__ h,
                                                       const void* __restrict__ wn,
                                                       const void* __restrict__ attn,
                                                       const void* __restrict__ delta,
                                                       const void* __restrict__ rel_emb,
                                                       const int* __restrict__ dst,
                                                       bf16* __restrict__ hWb,
                                                       float* __restrict__ s_src,
                                                       float* __restrict__ s_dst,
                                                       float* __restrict__ relW,
                                                       float* __restrict__ s_rel,
                                                       int* __restrict__ bcnt) {
    __shared__ int bh[NBUCK];
    const int bf = probe_bf(delta);
    const int wave = threadIdx.x >> 6;
    const int lane = threadIdx.x & 63;
    const int gw = blockIdx.x * 8 + wave;
    const int nwaves = gridDim.x * 8;
    // W1 column for this lane, in registers (no LDS/mem ops in the hot loop)
    float wreg[D];
    #pragma unroll
    for (int k = 0; k < D; k++) wreg[k] = ldf(wn, (long)k * D + lane, bf);
    const float a1 = ldf(attn, lane, bf);
    const float a2 = ldf(attn, D + lane, bf);
    // phase A: nodes, 4 per iteration (N_NODES % 4 == 0)
    for (int base = gw * 4; base < N_NODES; base += nwaves * 4) {
        float hv[4], acc[4];
        #pragma unroll
        for (int j = 0; j < 4; j++) {
            hv[j] = ldf(h, (long)(base + j) * D + lane, bf);
            acc[j] = 0.f;
        }
        #pragma unroll
        for (int j = 0; j < 4; j++) {
            float p1 = hv[j] * a1, p2 = hv[j] * a2;
            #pragma unroll
            for (int off = 32; off; off >>= 1) { p1 += __shfl_xor(p1, off); p2 += __shfl_xor(p2, off); }
            if (lane == 0) { s_src[base + j] = p1; s_dst[base + j] = p2; }
        }
        #pragma unroll
        for (int k = 0; k < D; k++) {
            float w = wreg[k];
            acc[0] += rl_f(hv[0], k) * w;
            acc[1] += rl_f(hv[1], k) * w;
            acc[2] += rl_f(hv[2], k) * w;
            acc[3] += rl_f(hv[3], k) * w;
        }
        #pragma unroll
        for (int j = 0; j < 4; j++) hWb[(long)(base + j) * D + lane] = f2b(acc[j]);
    }
    // phase B: relations (200 waves, per-k global W2 reads; L2-hot, tiny)
    const float a3 = ldf(attn, 2 * D + lane, bf);
    for (int r = gw; r < N_RELS; r += nwaves) {
        float rv = ldf(rel_emb, (long)r * D + lane, bf);
        float p3 = rv * a3;
        #pragma unroll
        for (int off = 32; off; off >>= 1) p3 += __shfl_xor(p3, off);
        if (lane == 0) s_rel[r] = p3;
        float acc = 0.f;
        #pragma unroll
        for (int k = 0; k < D; k++) {
            acc += rl_f(rv, k) * ldf(wn, (long)(D + k) * D + lane, bf);
        }
        relW[r * D + lane] = acc;
    }
    // phase C': coarse (dst>>9) histogram, LDS-aggregated
    for (int t = threadIdx.x; t < NBUCK; t += 512) bh[t] = 0;
    __syncthreads();
    for (int t = blockIdx.x * 512 + threadIdx.x; t < N_EDGES; t += gridDim.x * 512)
        atomicAdd(&bh[dst[t] >> 9], 1);
    __syncthreads();
    for (int t = threadIdx.x; t < NBUCK; t += 512) {
        int v = bh[t];
        if (v) atomicAdd(&bcnt[t], v);
    }
}

// exclusive scan of the 196 bucket counts; also primes bcursor and rowptr[N]
__global__ __launch_bounds__(256) void k_bscan(const int* __restrict__ bcnt,
                                               int* __restrict__ bbase,
                                               int* __restrict__ bcursor,
                                               int* __restrict__ rowptr) {
    __shared__ int s[256];
    const int tid = threadIdx.x;
    int v = (tid < NBUCK) ? bcnt[tid] : 0;
    s[tid] = v;
    __syncthreads();
    for (int off = 1; off < 256; off <<= 1) {
        int t = (tid >= off) ? s[tid - off] : 0;
        __syncthreads();
        s[tid] += t;
        __syncthreads();
    }
    if (tid < NBUCK) {
        int e = s[tid] - v;
        bbase[tid] = e;
        bcursor[tid] = e;
    }
    if (tid == 255) {
        bbase[NBUCK] = s[255];        // == N_EDGES
        rowptr[N_NODES] = s[255];
    }
}

// Pass B: compute full edge records {ex, src|rel<<17, dst&511}, bucket-sort a 4096-edge
// chunk in LDS, allocate per-bucket runs with ONE global atomic per (block,bucket),
// then copy out coalesced 16B runs. Replaces 1.6M scattered 8B writes (101 MB of
// partial-line HBM traffic) with ~26 MB of full-line writes.
__global__ __launch_bounds__(512, 2) void k_bin(const float* __restrict__ s_src,
                                                const float* __restrict__ s_dst,
                                                const float* __restrict__ s_rel,
                                                const void* __restrict__ etime,
                                                const void* __restrict__ delta,
                                                const int* __restrict__ src,
                                                const int* __restrict__ dst,
                                                const int* __restrict__ etype,
                                                int* __restrict__ bcursor,
                                                int4* __restrict__ binned) {
    __shared__ int lh[NBUCK];
    __shared__ int lbase[NBUCK];
    __shared__ int gbase[NBUCK];
    __shared__ int sc[256];
    __shared__ int4 stage[BIN_CHUNK];   // 64 KB (gfx950: up to 160 KB static LDS ok)
    const int bf = probe_bf(delta);
    const float df = ldf(delta, 0, bf);
    const int tid = threadIdx.x;
    const int base = blockIdx.x * BIN_CHUNK;
    for (int t = tid; t < NBUCK; t += 512) lh[t] = 0;
    __syncthreads();
    // phase 1: build records in registers, rank within block via LDS atomics
    int4 rc[8];
    int rk[8], bk[8];
    #pragma unroll
    for (int j = 0; j < 8; j++) {
        int e = base + j * 512 + tid;
        bk[j] = -1;
        if (e < N_EDGES) {
            int s = src[e], d = dst[e], r = etype[e];
            float scv = s_src[s] + s_dst[d] + s_rel[r];
            float lre = scv > 0.f ? scv : LEAKY * scv;
            float score = (-ldf(etime, e, bf) * df) * lre;
            rc[j].x = __float_as_int(__expf(score));
            rc[j].y = s | (r << 17);     // src < 2^17, rel < 256
            rc[j].z = d & 511;
            rc[j].w = 0;
            int b = d >> 9;
            bk[j] = b;
            rk[j] = atomicAdd(&lh[b], 1);
        }
    }
    __syncthreads();
    // phase 2: exclusive scan of lh -> lbase; per-bucket global base via single atomic
    if (tid < 256) sc[tid] = (tid < NBUCK) ? lh[tid] : 0;
    __syncthreads();
    for (int off = 1; off < 256; off <<= 1) {
        int t = 0;
        if (tid < 256 && tid >= off) t = sc[tid - off];
        __syncthreads();
        if (tid < 256) sc[tid] += t;
        __syncthreads();
    }
    if (tid < NBUCK) {
        lbase[tid] = sc[tid] - lh[tid];
        if (lh[tid] > 0) gbase[tid] = atomicAdd(&bcursor[tid], lh[tid]);
    }
    __syncthreads();
    // phase 3: bucket-sorted staging in LDS
    #pragma unroll
    for (int j = 0; j < 8; j++) {
        if (bk[j] >= 0) stage[lbase[bk[j]] + rk[j]] = rc[j];
    }
    __syncthreads();
    // phase 4: coalesced run copy-out (one wave per bucket, round-robin)
    const int wave = tid >> 6, lane = tid & 63;
    for (int b = wave; b < NBUCK; b += 8) {
        int n = lh[b];
        if (!n) continue;
        int ls = lbase[b];
        int gd = gbase[b];
        for (int k = lane; k < n; k += 64) binned[gd + k] = stage[ls + k];
    }
}

// Pass C: one workgroup per bucket. Fine histogram + scan in LDS (NO global atomics),
// write rowptr coalesced, scatter final 8B records inside a ~64 KB XCD-local region
// (full-line writebacks, no cross-XCD line sharing).
__global__ __launch_bounds__(1024) void k_bucket(const int4* __restrict__ binned,
                                                 const int* __restrict__ bbase,
                                                 int* __restrict__ rowptr,
                                                 int2* __restrict__ sorted) {
    __shared__ int fh[512];
    __shared__ int fc[512];
    __shared__ int sc[512];
    const int tid = threadIdx.x;
    const int b = blockIdx.x;
    const int n0 = b << 9;
    const int s0 = bbase[b], s1 = bbase[b + 1];
    if (tid < 512) { fh[tid] = 0; fc[tid] = 0; }
    __syncthreads();
    for (int i = s0 + tid; i < s1; i += 1024) atomicAdd(&fh[binned[i].z], 1);
    __syncthreads();
    if (tid < 512) sc[tid] = fh[tid];
    __syncthreads();
    for (int off = 1; off < 512; off <<= 1) {
        int t = 0;
        if (tid < 512 && tid >= off) t = sc[tid - off];
        __syncthreads();
        if (tid < 512) sc[tid] += t;
        __syncthreads();
    }
    int excl = 0;
    if (tid < 512) excl = sc[tid] - fh[tid];
    __syncthreads();
    if (tid < 512) {
        fh[tid] = excl;                               // fh now = exclusive offsets
        if (n0 + tid < N_NODES) rowptr[n0 + tid] = s0 + excl;
    }
    __syncthreads();
    for (int i = s0 + tid; i < s1; i += 1024) {
        int4 r = binned[i];                           // second read is L2-hot
        int p = s0 + fh[r.z] + atomicAdd(&fc[r.z], 1);
        sorted[p] = make_int2(r.x, r.y);
    }
}

// wave per node: chunk-sum of stored ex (1 shfl-reduction) + readlane-broadcast
// gather loop (unroll 4) + fused epilogue. No exp/max in this kernel.
__global__ __launch_bounds__(512, 6) void k_aggregate(const int* __restrict__ rowptr,
                                                      const int2* __restrict__ sorted,
                                                      const bf16* __restrict__ hWb,
                                                      const float* __restrict__ relW,
                                                      const void* __restrict__ h,
                                                      const void* __restrict__ loopW,
                                                      const void* __restrict__ evolveW,
                                                      const void* __restrict__ delta,
                                                      float* __restrict__ out) {
    const int bf = probe_bf(delta);
    __shared__ float WL[D * D];
    __shared__ float WE[D * D];
    for (int t = threadIdx.x; t < D * D; t += 512) { WL[t] = ldf(loopW, t, bf); WE[t] = ldf(evolveW, t, bf); }
    __syncthreads();
    const int wave = threadIdx.x >> 6;
    const int lane = threadIdx.x & 63;
    const int wstride = gridDim.x * 8;
    for (int i = blockIdx.x * 8 + wave; i < N_NODES; i += wstride) {
        int s0 = rowptr[i], e1 = rowptr[i + 1];
        float hv = ldf(h, (long)i * D + lane, bf);
        float acc;
        const float* W;
        if (e1 > s0) {
            float ls = 0.f;
            acc = 0.f;
            for (int c = s0; c < e1; c += 64) {
                int n = e1 - c; n = n > 64 ? 64 : n;
                float exl = 0.f; int pk = 0;
                if (lane < n) {
                    int2 rec = sorted[c + lane];
                    exl = __int_as_float(rec.x);
                    pk = rec.y;
                }
                float cs = exl;
                #pragma unroll
                for (int off = 32; off; off >>= 1) cs += __shfl_xor(cs, off);
                ls += cs;
                int j = 0;
                for (; j + 4 <= n; j += 4) {
                    float w0 = rl_f(exl, j),     w1 = rl_f(exl, j + 1);
                    float w2 = rl_f(exl, j + 2), w3 = rl_f(exl, j + 3);
                    int   p0 = rl_i(pk, j),      p1 = rl_i(pk, j + 1);
                    int   p2 = rl_i(pk, j + 2),  p3 = rl_i(pk, j + 3);
                    float m0 = b2f(hWb[(long)(p0 & 0x1FFFF) * D + lane]) + relW[(p0 >> 17) * D + lane];
                    float m1 = b2f(hWb[(long)(p1 & 0x1FFFF) * D + lane]) + relW[(p1 >> 17) * D + lane];
                    float m2 = b2f(hWb[(long)(p2 & 0x1FFFF) * D + lane]) + relW[(p2 >> 17) * D + lane];
                    float m3 = b2f(hWb[(long)(p3 & 0x1FFFF) * D + lane]) + relW[(p3 >> 17) * D + lane];
                    acc += w0 * m0;
                    acc += w1 * m1;
                    acc += w2 * m2;
                    acc += w3 * m3;
                }
                for (; j < n; j++) {
                    float w = rl_f(exl, j);
                    int   p = rl_i(pk, j);
                    acc += w * (b2f(hWb[(long)(p & 0x1FFFF) * D + lane]) + relW[(p >> 17) * D + lane]);
                }
            }
            acc *= 1.f / ls;    // ls > 0: every stored ex is exp(finite) > 0
            W = WL;
        } else {
            acc = hv;
            W = WE;
        }
        // fused epilogue: acc += h[i] @ W
        #pragma unroll
        for (int k = 0; k < D; k++) {
            acc += rl_f(hv, k) * W[k * D + lane];
        }
        out[(long)i * D + lane] = acc;
    }
}

// safe diagnostic fallback
__global__ __launch_bounds__(256) void k_fallback(float* __restrict__ out) {
    int t = blockIdx.x * blockDim.x + threadIdx.x;
    if (t < N_NODES * D) out[t] = 0.f;
}

extern "C" void kernel_launch(void* const* d_in, const int* in_sizes, int n_in,
                              void* d_out, int out_size, void* d_ws, size_t ws_size,
                              hipStream_t stream) {
    const void* h       = d_in[0];
    const void* rel_emb = d_in[1];
    const void* wn      = d_in[2];
    const void* attn    = d_in[3];
    const void* delta   = d_in[4];
    const void* loopW   = d_in[5];
    const void* evolveW = d_in[6];
    const void* etime   = d_in[7];
    const int*  src     = (const int*)d_in[8];
    const int*  dst     = (const int*)d_in[9];
    const int*  etype   = (const int*)d_in[10];
    float* out = (float*)d_out;

    char* ws = (char*)d_ws;
    size_t off = 0;
    auto alloc = [&](size_t bytes) -> void* {
        off = (off + 255) & ~(size_t)255;
        void* p = ws + off;
        off += bytes;
        return p;
    };
    int4*  binned  = (int4*) alloc((size_t)N_EDGES * 16);      // 25.6 MB
    int2*  sorted  = (int2*) alloc((size_t)N_EDGES * 8);       // 12.8 MB
    bf16*  hWb     = (bf16*) alloc((size_t)N_NODES * D * 2);   // 12.8 MB
    float* relW    = (float*)alloc((size_t)N_RELS * D * 4);    // 51.2 KB
    float* s_src   = (float*)alloc((size_t)N_NODES * 4);       //  0.4 MB
    float* s_dst   = (float*)alloc((size_t)N_NODES * 4);       //  0.4 MB
    float* s_rel   = (float*)alloc((size_t)N_RELS * 4);        //  0.8 KB
    int*   rowptr  = (int*)  alloc((size_t)(N_NODES + 1) * 4); //  0.4 MB
    int*   bcnt    = (int*)  alloc((size_t)NBUCK * 4);
    int*   bbase   = (int*)  alloc((size_t)(NBUCK + 1) * 4);
    int*   bcursor = (int*)  alloc((size_t)NBUCK * 4);

    if (ws_size < off) {
        k_fallback<<<(N_NODES * D + 255) / 256, 256, 0, stream>>>(out);
        return;
    }

    hipMemsetAsync(bcnt, 0, (size_t)NBUCK * 4, stream);
    k_fused_proj<<<1024, 512, 0, stream>>>(h, wn, attn, delta, rel_emb, dst,
                                           hWb, s_src, s_dst, relW, s_rel, bcnt);
    k_bscan<<<1, 256, 0, stream>>>(bcnt, bbase, bcursor, rowptr);
    k_bin<<<NBIN, 512, 0, stream>>>(s_src, s_dst, s_rel, etime, delta,
                                    src, dst, etype, bcursor, binned);
    k_bucket<<<NBUCK, 1024, 0, stream>>>(binned, bbase, rowptr, sorted);
    k_aggregate<<<4096, 512, 0, stream>>>(rowptr, sorted, hWb, relW, h, loopW, evolveW, delta, out);
}